// Round 5
// baseline (675.490 us; speedup 1.0000x reference)
//
#include <hip/hip_runtime.h>

#define N_NODES 10000
#define E_EDGES 320000
#define ND 256
#define ED 128

// ---- workspace layout (BYTE offsets); total ~26.3 MB ----
#define B_AM   0          // bf16 [10000][256]
#define B_BM   5120000    // bf16 [10000][256]
#define B_AE   10240000   // bf16 [10000][128]
#define B_BE   12800000   // bf16 [10000][128]
#define B_P1   15360000   // f32 [10000]
#define B_P2   15400960   // f32 [10000]
#define B_XA   15441920   // f32 [10000][256] accumulator
#define B_DEN  25681920   // f32 [10000]
#define B_CNT  25722880   // int [10000]
#define B_ROW  25763840   // int [10000]
#define B_CUR  25804800   // int [10000]
#define B_EID  25845760   // int [320000] CSR edge ids
#define B_WT   27125760   // bf16 weight tables, 425984 bytes

// weight table byte offsets within wtb; PACKED layout (wave-read order):
// per table: [wv(8)][kk(NK)][cf(CF)][lane(64)][j(8)] bf16  -> 1KB coalesced blocks
// col = wv*(N/8) + cf*16 + (lane&15);  k = kk*32 + (lane>>4)*8 + j
#define M0T 0
#define M1T 65536
#define M2T 196608
#define E0T 327680
#define E1T 360448
#define E2T 393216

// ---- LDS: four 16KB panels [64 rows][256B] + control ----
#define R0 0
#define R1 16384
#define R2 32768
#define R3 49152
#define AL_S  65536
#define SRC_S 65792
#define DST_S 66048
#define EID_S 66304
#define LDS_TOT 66560

#define BM 64

typedef float  float4v __attribute__((ext_vector_type(4)));
typedef short  short8  __attribute__((ext_vector_type(8)));

__device__ __forceinline__ unsigned short f2bf(float f) {
    unsigned int b = __float_as_uint(f);
    return (unsigned short)((b + 0x7FFFu + ((b >> 16) & 1u)) >> 16);
}
__device__ __forceinline__ float bf2f(unsigned short u) {
    return __uint_as_float(((unsigned int)u) << 16);
}
#define PK2(a,b) ((unsigned int)(a) | ((unsigned int)(b) << 16))

// ---------------- init: zero accumulators and CSR counters ----------------
__global__ void k_init(float* xa, float* den, int* cnt, int* cur) {
    int i = blockIdx.x * blockDim.x + threadIdx.x;
    int st = gridDim.x * blockDim.x;
    for (int j = i; j < N_NODES * ND; j += st) xa[j] = 0.f;
    for (int j = i; j < N_NODES; j += st) { den[j] = 0.f; cnt[j] = 0; cur[j] = 0; }
}

// ---------------- CSR build ----------------
__global__ void k_deg(const int* ei, int* cnt) {
    int e = blockIdx.x * 256 + threadIdx.x;
    if (e < E_EDGES) atomicAdd(&cnt[ei[e]], 1);
}

__global__ void k_scan(const int* cnt, int* rowstart) {   // 1 block, 256 threads
    __shared__ int part[256];
    int t = threadIdx.x;
    int base = t * 40;
    int s = 0;
    for (int i = 0; i < 40; i++) { int idx = base + i; if (idx < N_NODES) s += cnt[idx]; }
    part[t] = s;
    __syncthreads();
    if (t == 0) { int run = 0; for (int i = 0; i < 256; i++) { int v = part[i]; part[i] = run; run += v; } }
    __syncthreads();
    int run = part[t];
    for (int i = 0; i < 40; i++) {
        int idx = base + i;
        if (idx < N_NODES) { rowstart[idx] = run; run += cnt[idx]; }
    }
}

__global__ void k_fill(const int* ei, const int* rowstart, int* cur, int* eidcsr) {
    int e = blockIdx.x * 256 + threadIdx.x;
    if (e >= E_EDGES) return;
    int s = ei[e];
    int p = atomicAdd(&cur[s], 1);
    eidcsr[rowstart[s] + p] = e;
}

// ---------------- weight convert to bf16, PACKED in 8-way col-split order ----------------
__global__ void k_wconv(const float* mw0, const float* mw1, const float* mw2,
                        const float* ew0, const float* ew1, const float* ew2, char* wtb) {
    const int tot = 212992;
    for (int idx = blockIdx.x * blockDim.x + threadIdx.x; idx < tot;
         idx += gridDim.x * blockDim.x) {
        int local, K, N, base; const float* src;
        if (idx < 32768)       { local = idx;          K = 128; N = 256; src = mw0 + 512*256; base = M0T; }
        else if (idx < 98304)  { local = idx - 32768;  K = 256; N = 256; src = mw1;           base = M1T; }
        else if (idx < 163840) { local = idx - 98304;  K = 256; N = 256; src = mw2;           base = M2T; }
        else if (idx < 180224) { local = idx - 163840; K = 128; N = 128; src = ew0 + 512*128; base = E0T; }
        else if (idx < 196608) { local = idx - 180224; K = 128; N = 128; src = ew1;           base = E1T; }
        else                   { local = idx - 196608; K = 128; N = 128; src = ew2;           base = E2T; }
        int W8 = N / 8;
        int CF = W8 >> 4;       // 1 or 2
        int NK = K / 32;
        int t = local;
        int j    = t & 7;   t >>= 3;
        int lane = t & 63;  t >>= 6;
        int cf   = t % CF;  t /= CF;
        int kk   = t % NK;  t /= NK;
        int wvq  = t;       // 0..7
        int col = wvq * W8 + cf * 16 + (lane & 15);
        int k   = kk * 32 + (lane >> 4) * 8 + j;
        ((unsigned short*)(wtb + base))[local] = f2bf(src[k * N + col]);
    }
}

// ---------------- node precompute: [10000,256] @ [256,770] -> bf16 tables + f32 p1/p2 ----------------
__global__ __launch_bounds__(256) void k_nodepre(
    const float* na, const float* mw0, const float* ew0, const float* aw,
    const float* mb0, const float* eb0, const float* ab, char* wsb) {
    __shared__ float at[256 * 32];
    int tid = threadIdx.x;
    int r0 = blockIdx.x * 32;
    int nr = N_NODES - r0; if (nr > 32) nr = 32;
    {
        int r = tid & 31, kq = tid >> 5;
        if (r < nr) {
            const float* src = na + (size_t)(r0 + r) * ND + kq * 32;
            for (int i = 0; i < 32; i += 4) {
                float4 v = *(const float4*)(src + i);
                at[(kq*32 + i + 0)*32 + r] = v.x;
                at[(kq*32 + i + 1)*32 + r] = v.y;
                at[(kq*32 + i + 2)*32 + r] = v.z;
                at[(kq*32 + i + 3)*32 + r] = v.w;
            }
        } else {
            for (int i = 0; i < 32; i++) at[(kq*32 + i)*32 + r] = 0.f;
        }
    }
    __syncthreads();
    int c = blockIdx.y * 256 + tid;
    if (c >= 770) return;
    const float* wp; int wstep; float bias;
    unsigned short* opu = nullptr; float* opf = nullptr; int ostride;
    if (c < 256)      { wp = mw0 + c;                 wstep = 256; bias = mb0[c];     opu = (unsigned short*)(wsb + B_AM) + c;       ostride = 256; }
    else if (c < 512) { wp = mw0 + 65536 + (c - 256); wstep = 256; bias = 0.f;        opu = (unsigned short*)(wsb + B_BM) + (c-256); ostride = 256; }
    else if (c < 640) { wp = ew0 + (c - 512);         wstep = 128; bias = eb0[c-512]; opu = (unsigned short*)(wsb + B_AE) + (c-512); ostride = 128; }
    else if (c < 768) { wp = ew0 + 32768 + (c - 640); wstep = 128; bias = 0.f;        opu = (unsigned short*)(wsb + B_BE) + (c-640); ostride = 128; }
    else if (c == 768){ wp = aw;                      wstep = 1;   bias = ab[0];      opf = (float*)(wsb + B_P1);                    ostride = 1; }
    else              { wp = aw + 256;                wstep = 1;   bias = 0.f;        opf = (float*)(wsb + B_P2);                    ostride = 1; }
    float acc[32];
    #pragma unroll
    for (int r = 0; r < 32; r++) acc[r] = 0.f;
    for (int k = 0; k < 256; k++) {
        float w = wp[k * wstep];
        const float* a = &at[k * 32];
        #pragma unroll
        for (int r4 = 0; r4 < 8; r4++) {
            float4 a4 = *(const float4*)(a + r4 * 4);
            acc[r4*4+0] += a4.x * w; acc[r4*4+1] += a4.y * w;
            acc[r4*4+2] += a4.z * w; acc[r4*4+3] += a4.w * w;
        }
    }
    if (opu) { for (int r = 0; r < nr; r++) opu[(size_t)(r0 + r) * ostride] = f2bf(acc[r] + bias); }
    else     { for (int r = 0; r < nr; r++) opf[(size_t)(r0 + r)] = acc[r] + bias; }
}

// ---------------- fused per-edge MLP main kernel ----------------
struct DP {
    const float* ea; const int* ei; const int* csr;
    const unsigned short* Am; const unsigned short* Bm;
    const unsigned short* Ae; const unsigned short* Be;
    const float* p1; const float* p2; const float* aw;
    const float* mb1; const float* mb2; const float* eb1; const float* eb2;
    const char* wtb;
    float* xa; float* den; float* eout;
};

// panel pair addressing: 256-col buffers in (lo,hi), 128-col in lo.
__device__ __forceinline__ int pan_addr(int blo, int bhi, int row, int col) {
    int base = (col & 128) ? bhi : blo;
    return base + row * 256 + ((((col & 127)) * 2) ^ ((row & 7) << 4));
}
// fp32 dump addressing over all four panels: [64][256] f32, swizzled
__device__ __forceinline__ int dump_addr(int row, int col) {
    return row * 1024 + (((col * 4)) ^ ((row & 15) << 6));
}

// EPI: 0=m0(Am/Bm bf16 gather+relu->h) 1=bias+relu->h 2=m2(mb2,*ex,fp32 dump to LDS)
//      3=e0(Ae/Be bf16 gather+relu->h) 4=e2(eb2 -> eout scatter by eid)
// 8-way col split: each wave covers all 64 rows (rf=4) x NOUT/8 cols.
// B double-buffered in bbuf[2][4]; every phase starts with its chunk0 in bbuf[0]
// (all KH even -> parity invariant); last chunk-load fetches NEXT phase's chunk0.
template<int KTOT, int NOUT, int EPI, int NXT_N>
__device__ __forceinline__ void do_gemm(char* sm, const DP& p,
                                        int a_lo, int a_hi, const char* wt,
                                        int h_lo, int h_hi, const float* bias,
                                        const char* wt_next, short8 (&bbuf)[2][4],
                                        int wv, int lane) {
    constexpr int W8  = NOUT / 8;
    constexpr int CF  = W8 / 16;                 // 1 or 2
    constexpr int NK  = KTOT / 32;
    constexpr int NB  = NK * CF;                 // 1KB blocks per wave
    constexpr int NCH = (NB / 2 > 4) ? 4 : NB / 2;   // chunk size (2 or 4)
    constexpr int KH  = NB / NCH;                // chunks (2 or 4), always even
    constexpr int NKH = NK / KH;                 // k-steps per chunk (2)
    const int l15 = lane & 15, lg = lane >> 4;
    const int cb = wv * W8;
    const float4v vz = {0.f, 0.f, 0.f, 0.f};
    float4v acc[4][CF];
    #pragma unroll
    for (int i = 0; i < 4; i++)
        #pragma unroll
        for (int j = 0; j < CF; j++) acc[i][j] = vz;
    __syncthreads();
    #pragma unroll
    for (int h = 0; h < KH; h++) {
        if (h + 1 < KH) {
            #pragma unroll
            for (int i = 0; i < NCH; i++)
                bbuf[(h+1)&1][i] = *(const short8*)(wt + ((size_t)((h+1)*NCH + i) * 64 + lane) * 16);
        } else if constexpr (NXT_N > 0) {
            #pragma unroll
            for (int i = 0; i < NXT_N; i++)
                bbuf[(h+1)&1][i] = *(const short8*)(wt_next + ((size_t)i * 64 + lane) * 16);
        }
        #pragma unroll
        for (int ks = 0; ks < NKH; ks++) {
            int ke = (h * NKH + ks) * 32 + lg * 8;
            short8 a[4];
            #pragma unroll
            for (int rf = 0; rf < 4; rf++)
                a[rf] = *(const short8*)(sm + pan_addr(a_lo, a_hi, rf * 16 + l15, ke));
            #pragma unroll
            for (int rf = 0; rf < 4; rf++)
                #pragma unroll
                for (int cf = 0; cf < CF; cf++)
                    acc[rf][cf] = __builtin_amdgcn_mfma_f32_16x16x32_bf16(a[rf], bbuf[h&1][ks*CF+cf], acc[rf][cf], 0, 0, 0);
        }
    }
    if constexpr (EPI == 2) __syncthreads();   // dump overwrites A panels
    const int*   srcid = (const int*)(sm + SRC_S);
    const int*   dstid = (const int*)(sm + DST_S);
    const int*   eid   = (const int*)(sm + EID_S);
    const float* exv   = (const float*)(sm + AL_S);
    #pragma unroll
    for (int rf = 0; rf < 4; rf++)
        #pragma unroll
        for (int cf = 0; cf < CF; cf++)
            #pragma unroll
            for (int j = 0; j < 4; j++) {
                int row = rf * 16 + lg * 4 + j;
                int col = cb + cf * 16 + l15;
                float v = acc[rf][cf][j];
                if constexpr (EPI == 0) {
                    v += bf2f(p.Am[(size_t)srcid[row] * ND + col]) + bf2f(p.Bm[(size_t)dstid[row] * ND + col]);
                    v = fmaxf(v, 0.f);
                    *(unsigned short*)(sm + pan_addr(h_lo, h_hi, row, col)) = f2bf(v);
                } else if constexpr (EPI == 1) {
                    v += bias[col]; v = fmaxf(v, 0.f);
                    *(unsigned short*)(sm + pan_addr(h_lo, h_hi, row, col)) = f2bf(v);
                } else if constexpr (EPI == 2) {
                    v = (v + p.mb2[col]) * exv[row];
                    *(float*)(sm + dump_addr(row, col)) = v;
                } else if constexpr (EPI == 3) {
                    v += bf2f(p.Ae[(size_t)srcid[row] * ED + col]) + bf2f(p.Be[(size_t)dstid[row] * ED + col]);
                    v = fmaxf(v, 0.f);
                    *(unsigned short*)(sm + pan_addr(h_lo, h_hi, row, col)) = f2bf(v);
                } else {
                    v += p.eb2[col];
                    p.eout[(size_t)eid[row] * ED + col] = v;
                }
            }
}

__global__ __launch_bounds__(512, 4) void k_main(DP p) {
    extern __shared__ char sm[];
    const int tid = threadIdx.x;
    const int lane = tid & 63, wv = tid >> 6;
    const int s0 = blockIdx.x * BM;

    // per-wave packed-weight bases (wave region = NK*CF KB)
    const char* wtE0 = p.wtb + E0T + (size_t)wv * 4096;
    const char* wtE1 = p.wtb + E1T + (size_t)wv * 4096;
    const char* wtE2 = p.wtb + E2T + (size_t)wv * 4096;
    const char* wtM0 = p.wtb + M0T + (size_t)wv * 8192;
    const char* wtM1 = p.wtb + M1T + (size_t)wv * 16384;
    const char* wtM2 = p.wtb + M2T + (size_t)wv * 16384;

    short8 bbuf[2][4];
    // prologue: e0 chunk0 -> bbuf[0] (issued before staging; hidden under it)
    #pragma unroll
    for (int i = 0; i < 2; i++)
        bbuf[0][i] = *(const short8*)(wtE0 + ((size_t)i * 64 + lane) * 16);

    if (tid < BM) {
        int eid = p.csr[s0 + tid];
        ((int*)(sm + EID_S))[tid] = eid;
        ((int*)(sm + SRC_S))[tid] = p.ei[eid];
        ((int*)(sm + DST_S))[tid] = p.ei[E_EDGES + eid];
    }
    // stage: gather edge_attr row, pack bf16 swizzled into R0, fused att+exp
    {
        int r = tid >> 3, cq = tid & 7;             // 8 threads x 16 floats per row
        int eid = p.csr[s0 + r];
        const float4* src = (const float4*)(p.ea + (size_t)eid * ED + cq * 16);
        const float4* wvp = (const float4*)(p.aw + 512 + cq * 16);
        int s = (r & 7) << 4;
        float4 v0 = src[0], v1 = src[1], v2 = src[2], v3 = src[3];
        float4 w0 = wvp[0], w1 = wvp[1], w2 = wvp[2], w3 = wvp[3];
        float sd = v0.x*w0.x + v0.y*w0.y + v0.z*w0.z + v0.w*w0.w
                 + v1.x*w1.x + v1.y*w1.y + v1.z*w1.z + v1.w*w1.w
                 + v2.x*w2.x + v2.y*w2.y + v2.z*w2.z + v2.w*w2.w
                 + v3.x*w3.x + v3.y*w3.y + v3.z*w3.z + v3.w*w3.w;
        unsigned short u[16] = {f2bf(v0.x),f2bf(v0.y),f2bf(v0.z),f2bf(v0.w),
                                f2bf(v1.x),f2bf(v1.y),f2bf(v1.z),f2bf(v1.w),
                                f2bf(v2.x),f2bf(v2.y),f2bf(v2.z),f2bf(v2.w),
                                f2bf(v3.x),f2bf(v3.y),f2bf(v3.z),f2bf(v3.w)};
        int cb = cq * 32;
        *(uint4*)(sm + R0 + r*256 + (cb ^ s)) =
            make_uint4(PK2(u[0],u[1]), PK2(u[2],u[3]), PK2(u[4],u[5]), PK2(u[6],u[7]));
        *(uint4*)(sm + R0 + r*256 + ((cb + 16) ^ s)) =
            make_uint4(PK2(u[8],u[9]), PK2(u[10],u[11]), PK2(u[12],u[13]), PK2(u[14],u[15]));
        // reduce att over the 8 lanes of this row
        sd += __shfl_xor(sd, 1); sd += __shfl_xor(sd, 2); sd += __shfl_xor(sd, 4);
        if (cq == 0) {
            int sn = p.ei[eid];
            int dn = p.ei[E_EDGES + eid];
            float a = sd + p.p1[sn] + p.p2[dn];
            float ex = __expf(a);                 // max-free: att bounded ~|6|
            ((float*)(sm + AL_S))[r] = ex;
            unsafeAtomicAdd(&p.den[sn], ex);
        }
    }
    // e-chain (ea in R0 live through m0)
    do_gemm<128,128,3,2>(sm, p, R0, 0,  wtE0, R1, 0,  nullptr, wtE1, bbuf, wv, lane);
    do_gemm<128,128,1,2>(sm, p, R1, 0,  wtE1, R2, 0,  p.eb1,   wtE2, bbuf, wv, lane);
    do_gemm<128,128,4,4>(sm, p, R2, 0,  wtE2, 0,  0,  nullptr, wtM0, bbuf, wv, lane);
    // m-chain: h0m -> (R1,R2), h1m -> (R0,R3), m2 dumps fp32 to R0..R3
    do_gemm<128,256,0,4>(sm, p, R0, 0,  wtM0, R1, R2, nullptr, wtM1, bbuf, wv, lane);
    do_gemm<256,256,1,4>(sm, p, R1, R2, wtM1, R0, R3, p.mb1,   wtM2, bbuf, wv, lane);
    do_gemm<256,256,2,0>(sm, p, R0, R3, wtM2, 0,  0,  nullptr, nullptr, bbuf, wv, lane);
    __syncthreads();
    // segmented reduction over sorted src: one atomic per (segment, col)
    {
        const int* srcid = (const int*)(sm + SRC_S);
        int h = tid >> 8;          // 0/1: rows 0..31 / 32..63
        int c = tid & 255;
        int rend = h * 32 + 31;
        float acc = 0.f;
        for (int r = h * 32; r <= rend; r++) {
            acc += *(const float*)(sm + dump_addr(r, c));
            if (r == rend || srcid[r + 1] != srcid[r]) {
                unsafeAtomicAdd(&p.xa[(size_t)srcid[r] * ND + c], acc);
                acc = 0.f;
            }
        }
    }
}

// ---------------- normalize: x_out = xa / den ----------------
__global__ void k_norm(const float* xa, const float* den, float* xout) {
    int i = blockIdx.x * 256 + threadIdx.x;
    if (i >= N_NODES * ND) return;
    float d = den[i >> 8];
    xout[i] = (d > 0.f) ? xa[i] / d : 0.f;
}

extern "C" void kernel_launch(void* const* d_in, const int* in_sizes, int n_in,
                              void* d_out, int out_size, void* d_ws, size_t ws_size,
                              hipStream_t stream) {
    const float* na  = (const float*)d_in[0];
    const float* ea  = (const float*)d_in[1];
    const int*   ei  = (const int*)d_in[2];
    const float* mw0 = (const float*)d_in[3];
    const float* mb0 = (const float*)d_in[4];
    const float* mw1 = (const float*)d_in[5];
    const float* mb1 = (const float*)d_in[6];
    const float* mw2 = (const float*)d_in[7];
    const float* mb2 = (const float*)d_in[8];
    const float* ew0 = (const float*)d_in[9];
    const float* eb0 = (const float*)d_in[10];
    const float* ew1 = (const float*)d_in[11];
    const float* eb1 = (const float*)d_in[12];
    const float* ew2 = (const float*)d_in[13];
    const float* eb2 = (const float*)d_in[14];
    const float* aw  = (const float*)d_in[15];
    const float* ab  = (const float*)d_in[16];
    float* out = (float*)d_out;
    char*  wsb = (char*)d_ws;

    float* xout = out;
    float* eout = out + (size_t)N_NODES * ND;

    float* xa  = (float*)(wsb + B_XA);
    float* den = (float*)(wsb + B_DEN);
    int*   cnt = (int*)(wsb + B_CNT);
    int*   row = (int*)(wsb + B_ROW);
    int*   cur = (int*)(wsb + B_CUR);
    int*   eidcsr = (int*)(wsb + B_EID);

    k_init<<<512, 256, 0, stream>>>(xa, den, cnt, cur);
    k_deg<<<1250, 256, 0, stream>>>(ei, cnt);
    k_scan<<<1, 256, 0, stream>>>(cnt, row);
    k_fill<<<1250, 256, 0, stream>>>(ei, row, cur, eidcsr);
    k_wconv<<<256, 256, 0, stream>>>(mw0, mw1, mw2, ew0, ew1, ew2, wsb + B_WT);
    k_nodepre<<<dim3(313, 4), 256, 0, stream>>>(na, mw0, ew0, aw, mb0, eb0, ab, wsb);

    DP p{ea, ei, eidcsr,
         (const unsigned short*)(wsb + B_AM), (const unsigned short*)(wsb + B_BM),
         (const unsigned short*)(wsb + B_AE), (const unsigned short*)(wsb + B_BE),
         (const float*)(wsb + B_P1), (const float*)(wsb + B_P2), aw,
         mb1, mb2, eb1, eb2, (const char*)(wsb + B_WT), xa, den, eout};
    hipFuncSetAttribute((const void*)k_main, hipFuncAttributeMaxDynamicSharedMemorySize, LDS_TOT);
    k_main<<<E_EDGES / BM, 512, LDS_TOT, stream>>>(p);
    k_norm<<<10000, 256, 0, stream>>>(xa, den, xout);
}

// Round 6
// 620.227 us; speedup vs baseline: 1.0891x; 1.0891x over previous
//
#include <hip/hip_runtime.h>

#define N_NODES 10000
#define E_EDGES 320000
#define ND 256
#define ED 128

// ---- workspace layout (BYTE offsets); total ~26.3 MB ----
#define B_AM   0          // bf16 [10000][256]
#define B_BM   5120000    // bf16 [10000][256]
#define B_AE   10240000   // bf16 [10000][128]
#define B_BE   12800000   // bf16 [10000][128]
#define B_P1   15360000   // f32 [10000]
#define B_P2   15400960   // f32 [10000]
#define B_XA   15441920   // f32 [10000][256] accumulator
#define B_DEN  25681920   // f32 [10000]
#define B_CNT  25722880   // int [10000]
#define B_ROW  25763840   // int [10000]
#define B_CUR  25804800   // int [10000]
#define B_EID  25845760   // int [320000] CSR edge ids
#define B_WT   27125760   // bf16 weight tables, 425984 bytes

// weight table byte offsets within wtb; PACKED layout (4 col-groups, wave-read order):
// per table: [wc(4)][kk(NK)][cf(CF)][lane(64)][j(8)] bf16 -> 1KB coalesced blocks
// col = wc*(N/4) + cf*16 + (lane&15);  k = kk*32 + (lane>>4)*8 + j
#define M0T 0
#define M1T 65536
#define M2T 196608
#define E0T 327680
#define E1T 360448
#define E2T 393216

// ---- LDS: four 16KB panels [64 rows][256B] + control ----
#define R0 0
#define R1 16384
#define R2 32768
#define R3 49152
#define AL_S  65536
#define SRC_S 65792
#define DST_S 66048
#define EID_S 66304
#define LDS_TOT 66560

#define BM 64

typedef float  float4v __attribute__((ext_vector_type(4)));
typedef short  short8  __attribute__((ext_vector_type(8)));

__device__ __forceinline__ unsigned short f2bf(float f) {
    unsigned int b = __float_as_uint(f);
    return (unsigned short)((b + 0x7FFFu + ((b >> 16) & 1u)) >> 16);
}
__device__ __forceinline__ float bf2f(unsigned short u) {
    return __uint_as_float(((unsigned int)u) << 16);
}
#define PK2(a,b) ((unsigned int)(a) | ((unsigned int)(b) << 16))

// ---------------- init: zero accumulators and CSR counters ----------------
__global__ void k_init(float* xa, float* den, int* cnt, int* cur) {
    int i = blockIdx.x * blockDim.x + threadIdx.x;
    int st = gridDim.x * blockDim.x;
    for (int j = i; j < N_NODES * ND; j += st) xa[j] = 0.f;
    for (int j = i; j < N_NODES; j += st) { den[j] = 0.f; cnt[j] = 0; cur[j] = 0; }
}

// ---------------- CSR build ----------------
__global__ void k_deg(const int* ei, int* cnt) {
    int e = blockIdx.x * 256 + threadIdx.x;
    if (e < E_EDGES) atomicAdd(&cnt[ei[e]], 1);
}

__global__ void k_scan(const int* cnt, int* rowstart) {   // 1 block, 256 threads
    __shared__ int part[256];
    int t = threadIdx.x;
    int base = t * 40;
    int s = 0;
    for (int i = 0; i < 40; i++) { int idx = base + i; if (idx < N_NODES) s += cnt[idx]; }
    part[t] = s;
    __syncthreads();
    if (t == 0) { int run = 0; for (int i = 0; i < 256; i++) { int v = part[i]; part[i] = run; run += v; } }
    __syncthreads();
    int run = part[t];
    for (int i = 0; i < 40; i++) {
        int idx = base + i;
        if (idx < N_NODES) { rowstart[idx] = run; run += cnt[idx]; }
    }
}

__global__ void k_fill(const int* ei, const int* rowstart, int* cur, int* eidcsr) {
    int e = blockIdx.x * 256 + threadIdx.x;
    if (e >= E_EDGES) return;
    int s = ei[e];
    int p = atomicAdd(&cur[s], 1);
    eidcsr[rowstart[s] + p] = e;
}

// ---------------- weight convert to bf16, PACKED in 4-group col-split order ----------------
__global__ void k_wconv(const float* mw0, const float* mw1, const float* mw2,
                        const float* ew0, const float* ew1, const float* ew2, char* wtb) {
    const int tot = 212992;
    for (int idx = blockIdx.x * blockDim.x + threadIdx.x; idx < tot;
         idx += gridDim.x * blockDim.x) {
        int local, K, N, base; const float* src;
        if (idx < 32768)       { local = idx;          K = 128; N = 256; src = mw0 + 512*256; base = M0T; }
        else if (idx < 98304)  { local = idx - 32768;  K = 256; N = 256; src = mw1;           base = M1T; }
        else if (idx < 163840) { local = idx - 98304;  K = 256; N = 256; src = mw2;           base = M2T; }
        else if (idx < 180224) { local = idx - 163840; K = 128; N = 128; src = ew0 + 512*128; base = E0T; }
        else if (idx < 196608) { local = idx - 180224; K = 128; N = 128; src = ew1;           base = E1T; }
        else                   { local = idx - 196608; K = 128; N = 128; src = ew2;           base = E2T; }
        int W4 = N / 4;
        int CF = W4 >> 4;       // 4 or 2
        int NK = K / 32;
        int t = local;
        int j    = t & 7;   t >>= 3;
        int lane = t & 63;  t >>= 6;
        int cf   = t % CF;  t /= CF;
        int kk   = t % NK;  t /= NK;
        int wc   = t;       // 0..3
        int col = wc * W4 + cf * 16 + (lane & 15);
        int k   = kk * 32 + (lane >> 4) * 8 + j;
        ((unsigned short*)(wtb + base))[local] = f2bf(src[k * N + col]);
    }
}

// ---------------- node precompute: [10000,256] @ [256,770] -> bf16 tables + f32 p1/p2 ----------------
__global__ __launch_bounds__(256) void k_nodepre(
    const float* na, const float* mw0, const float* ew0, const float* aw,
    const float* mb0, const float* eb0, const float* ab, char* wsb) {
    __shared__ float at[256 * 32];
    int tid = threadIdx.x;
    int r0 = blockIdx.x * 32;
    int nr = N_NODES - r0; if (nr > 32) nr = 32;
    {
        int r = tid & 31, kq = tid >> 5;
        if (r < nr) {
            const float* src = na + (size_t)(r0 + r) * ND + kq * 32;
            for (int i = 0; i < 32; i += 4) {
                float4 v = *(const float4*)(src + i);
                at[(kq*32 + i + 0)*32 + r] = v.x;
                at[(kq*32 + i + 1)*32 + r] = v.y;
                at[(kq*32 + i + 2)*32 + r] = v.z;
                at[(kq*32 + i + 3)*32 + r] = v.w;
            }
        } else {
            for (int i = 0; i < 32; i++) at[(kq*32 + i)*32 + r] = 0.f;
        }
    }
    __syncthreads();
    int c = blockIdx.y * 256 + tid;
    if (c >= 770) return;
    const float* wp; int wstep; float bias;
    unsigned short* opu = nullptr; float* opf = nullptr; int ostride;
    if (c < 256)      { wp = mw0 + c;                 wstep = 256; bias = mb0[c];     opu = (unsigned short*)(wsb + B_AM) + c;       ostride = 256; }
    else if (c < 512) { wp = mw0 + 65536 + (c - 256); wstep = 256; bias = 0.f;        opu = (unsigned short*)(wsb + B_BM) + (c-256); ostride = 256; }
    else if (c < 640) { wp = ew0 + (c - 512);         wstep = 128; bias = eb0[c-512]; opu = (unsigned short*)(wsb + B_AE) + (c-512); ostride = 128; }
    else if (c < 768) { wp = ew0 + 32768 + (c - 640); wstep = 128; bias = 0.f;        opu = (unsigned short*)(wsb + B_BE) + (c-640); ostride = 128; }
    else if (c == 768){ wp = aw;                      wstep = 1;   bias = ab[0];      opf = (float*)(wsb + B_P1);                    ostride = 1; }
    else              { wp = aw + 256;                wstep = 1;   bias = 0.f;        opf = (float*)(wsb + B_P2);                    ostride = 1; }
    float acc[32];
    #pragma unroll
    for (int r = 0; r < 32; r++) acc[r] = 0.f;
    for (int k = 0; k < 256; k++) {
        float w = wp[k * wstep];
        const float* a = &at[k * 32];
        #pragma unroll
        for (int r4 = 0; r4 < 8; r4++) {
            float4 a4 = *(const float4*)(a + r4 * 4);
            acc[r4*4+0] += a4.x * w; acc[r4*4+1] += a4.y * w;
            acc[r4*4+2] += a4.z * w; acc[r4*4+3] += a4.w * w;
        }
    }
    if (opu) { for (int r = 0; r < nr; r++) opu[(size_t)(r0 + r) * ostride] = f2bf(acc[r] + bias); }
    else     { for (int r = 0; r < nr; r++) opf[(size_t)(r0 + r)] = acc[r] + bias; }
}

// ---------------- fused per-edge MLP main kernel ----------------
struct DP {
    const float* ea; const int* ei; const int* csr;
    const unsigned short* Am; const unsigned short* Bm;
    const unsigned short* Ae; const unsigned short* Be;
    const float* p1; const float* p2; const float* aw;
    const float* mb1; const float* mb2; const float* eb1; const float* eb2;
    const char* wtb;
    float* xa; float* den; float* eout;
};

// panel pair addressing: 256-col buffers in (lo,hi), 128-col in lo.
__device__ __forceinline__ int pan_addr(int blo, int bhi, int row, int col) {
    int base = (col & 128) ? bhi : blo;
    return base + row * 256 + ((((col & 127)) * 2) ^ ((row & 7) << 4));
}
// fp32 dump addressing over all four panels: [64][256] f32, swizzled
__device__ __forceinline__ int dump_addr(int row, int col) {
    return row * 1024 + (((col * 4)) ^ ((row & 15) << 6));
}

// EPI: 0=m0(Am/Bm bf16 gather+relu->h) 1=bias+relu->h 2=m2(mb2,*ex,fp32 dump to LDS)
//      3=e0(Ae/Be bf16 gather+relu->h) 4=e2(eb2 -> eout scatter by eid)
// 2(row)x4(col) wave split. B double-buffered in bbuf[2][4], chunk = 4x1KB blocks;
// all KH even -> every phase starts with its chunk0 in bbuf[0]; the last chunk-load
// of phase i fetches phase i+1's chunk0 (crosses the barrier in-flight).
// A explicitly software-pipelined: areg[2][2], k-step k+1 loads issued before MFMAs of k.
template<int KTOT, int NOUT, int EPI, int NXT_N>
__device__ __forceinline__ void do_gemm(char* sm, const DP& p,
                                        int a_lo, int a_hi, const char* wt,
                                        int h_lo, int h_hi, const float* bias,
                                        const char* wt_next, short8 (&bbuf)[2][4],
                                        int wr, int wc, int lane) {
    constexpr int WCOL = NOUT / 4;
    constexpr int CF   = WCOL / 16;              // 4 or 2
    constexpr int NK   = KTOT / 32;
    constexpr int KH   = NK * CF / 4;            // chunks of 4 blocks: 2,4,8 (even)
    constexpr int NKH  = NK / KH;                // k-steps per chunk: 2 or 1
    const int l15 = lane & 15, lg = lane >> 4;
    const float4v vz = {0.f, 0.f, 0.f, 0.f};
    float4v acc[2][CF];
    #pragma unroll
    for (int i = 0; i < 2; i++)
        #pragma unroll
        for (int j = 0; j < CF; j++) acc[i][j] = vz;
    __syncthreads();
    short8 areg[2][2];
    #pragma unroll
    for (int rf = 0; rf < 2; rf++)
        areg[0][rf] = *(const short8*)(sm + pan_addr(a_lo, a_hi, wr*32 + rf*16 + l15, lg*8));
    #pragma unroll
    for (int h = 0; h < KH; h++) {
        if (h + 1 < KH) {
            #pragma unroll
            for (int i = 0; i < 4; i++)
                bbuf[(h+1)&1][i] = *(const short8*)(wt + ((size_t)((h+1)*4 + i) * 64 + lane) * 16);
        } else if constexpr (NXT_N > 0) {
            #pragma unroll
            for (int i = 0; i < NXT_N; i++)
                bbuf[(h+1)&1][i] = *(const short8*)(wt_next + ((size_t)i * 64 + lane) * 16);
        }
        #pragma unroll
        for (int ks = 0; ks < NKH; ks++) {
            int kstep = h * NKH + ks;
            if (kstep + 1 < NK) {
                int ke = (kstep + 1) * 32 + lg * 8;
                #pragma unroll
                for (int rf = 0; rf < 2; rf++)
                    areg[(kstep+1)&1][rf] = *(const short8*)(sm + pan_addr(a_lo, a_hi, wr*32 + rf*16 + l15, ke));
            }
            #pragma unroll
            for (int rf = 0; rf < 2; rf++)
                #pragma unroll
                for (int cf = 0; cf < CF; cf++)
                    acc[rf][cf] = __builtin_amdgcn_mfma_f32_16x16x32_bf16(areg[kstep&1][rf], bbuf[h&1][ks*CF+cf], acc[rf][cf], 0, 0, 0);
        }
    }
    if constexpr (EPI == 2) __syncthreads();   // dump overwrites A panels
    const int*   srcid = (const int*)(sm + SRC_S);
    const int*   dstid = (const int*)(sm + DST_S);
    const int*   eid   = (const int*)(sm + EID_S);
    const float* exv   = (const float*)(sm + AL_S);
    #pragma unroll
    for (int rf = 0; rf < 2; rf++)
        #pragma unroll
        for (int cf = 0; cf < CF; cf++)
            #pragma unroll
            for (int j = 0; j < 4; j++) {
                int row = wr * 32 + rf * 16 + lg * 4 + j;
                int col = wc * WCOL + cf * 16 + l15;
                float v = acc[rf][cf][j];
                if constexpr (EPI == 0) {
                    v += bf2f(p.Am[(size_t)srcid[row] * ND + col]) + bf2f(p.Bm[(size_t)dstid[row] * ND + col]);
                    v = fmaxf(v, 0.f);
                    *(unsigned short*)(sm + pan_addr(h_lo, h_hi, row, col)) = f2bf(v);
                } else if constexpr (EPI == 1) {
                    v += bias[col]; v = fmaxf(v, 0.f);
                    *(unsigned short*)(sm + pan_addr(h_lo, h_hi, row, col)) = f2bf(v);
                } else if constexpr (EPI == 2) {
                    v = (v + p.mb2[col]) * exv[row];
                    *(float*)(sm + dump_addr(row, col)) = v;
                } else if constexpr (EPI == 3) {
                    v += bf2f(p.Ae[(size_t)srcid[row] * ED + col]) + bf2f(p.Be[(size_t)dstid[row] * ED + col]);
                    v = fmaxf(v, 0.f);
                    *(unsigned short*)(sm + pan_addr(h_lo, h_hi, row, col)) = f2bf(v);
                } else {
                    v += p.eb2[col];
                    p.eout[(size_t)eid[row] * ED + col] = v;
                }
            }
}

__global__ __launch_bounds__(512, 4) void k_main(DP p) {
    extern __shared__ char sm[];
    const int tid = threadIdx.x;
    const int lane = tid & 63, wv = tid >> 6;
    const int wr = wv >> 2, wc = wv & 3;
    const int s0 = blockIdx.x * BM;

    // per-wave packed-weight bases (col-group region = NK*CF KB)
    const char* wtE0 = p.wtb + E0T + (size_t)wc * 8192;
    const char* wtE1 = p.wtb + E1T + (size_t)wc * 8192;
    const char* wtE2 = p.wtb + E2T + (size_t)wc * 8192;
    const char* wtM0 = p.wtb + M0T + (size_t)wc * 16384;
    const char* wtM1 = p.wtb + M1T + (size_t)wc * 32768;
    const char* wtM2 = p.wtb + M2T + (size_t)wc * 32768;

    short8 bbuf[2][4];
    // prologue: e0 chunk0 -> bbuf[0] (issued before staging; hidden under it)
    #pragma unroll
    for (int i = 0; i < 4; i++)
        bbuf[0][i] = *(const short8*)(wtE0 + ((size_t)i * 64 + lane) * 16);

    if (tid < BM) {
        int eid = p.csr[s0 + tid];
        ((int*)(sm + EID_S))[tid] = eid;
        ((int*)(sm + SRC_S))[tid] = p.ei[eid];
        ((int*)(sm + DST_S))[tid] = p.ei[E_EDGES + eid];
    }
    // stage: gather edge_attr row, pack bf16 swizzled into R0, fused att+exp
    {
        int r = tid >> 3, cq = tid & 7;             // 8 threads x 16 floats per row
        int eid = p.csr[s0 + r];
        const float4* src = (const float4*)(p.ea + (size_t)eid * ED + cq * 16);
        const float4* wvp = (const float4*)(p.aw + 512 + cq * 16);
        int s = (r & 7) << 4;
        float4 v0 = src[0], v1 = src[1], v2 = src[2], v3 = src[3];
        float4 w0 = wvp[0], w1 = wvp[1], w2 = wvp[2], w3 = wvp[3];
        float sd = v0.x*w0.x + v0.y*w0.y + v0.z*w0.z + v0.w*w0.w
                 + v1.x*w1.x + v1.y*w1.y + v1.z*w1.z + v1.w*w1.w
                 + v2.x*w2.x + v2.y*w2.y + v2.z*w2.z + v2.w*w2.w
                 + v3.x*w3.x + v3.y*w3.y + v3.z*w3.z + v3.w*w3.w;
        unsigned short u[16] = {f2bf(v0.x),f2bf(v0.y),f2bf(v0.z),f2bf(v0.w),
                                f2bf(v1.x),f2bf(v1.y),f2bf(v1.z),f2bf(v1.w),
                                f2bf(v2.x),f2bf(v2.y),f2bf(v2.z),f2bf(v2.w),
                                f2bf(v3.x),f2bf(v3.y),f2bf(v3.z),f2bf(v3.w)};
        int cb = cq * 32;
        *(uint4*)(sm + R0 + r*256 + (cb ^ s)) =
            make_uint4(PK2(u[0],u[1]), PK2(u[2],u[3]), PK2(u[4],u[5]), PK2(u[6],u[7]));
        *(uint4*)(sm + R0 + r*256 + ((cb + 16) ^ s)) =
            make_uint4(PK2(u[8],u[9]), PK2(u[10],u[11]), PK2(u[12],u[13]), PK2(u[14],u[15]));
        // reduce att over the 8 lanes of this row
        sd += __shfl_xor(sd, 1); sd += __shfl_xor(sd, 2); sd += __shfl_xor(sd, 4);
        if (cq == 0) {
            int sn = p.ei[eid];
            int dn = p.ei[E_EDGES + eid];
            float a = sd + p.p1[sn] + p.p2[dn];
            float ex = __expf(a);                 // max-free: att bounded ~|6|
            ((float*)(sm + AL_S))[r] = ex;
            unsafeAtomicAdd(&p.den[sn], ex);
        }
    }
    // e-chain (ea in R0 live through m0)
    do_gemm<128,128,3,4>(sm, p, R0, 0,  wtE0, R1, 0,  nullptr, wtE1, bbuf, wr, wc, lane);
    do_gemm<128,128,1,4>(sm, p, R1, 0,  wtE1, R2, 0,  p.eb1,   wtE2, bbuf, wr, wc, lane);
    do_gemm<128,128,4,4>(sm, p, R2, 0,  wtE2, 0,  0,  nullptr, wtM0, bbuf, wr, wc, lane);
    // m-chain: h0m -> (R1,R2), h1m -> (R0,R3), m2 dumps fp32 to R0..R3
    do_gemm<128,256,0,4>(sm, p, R0, 0,  wtM0, R1, R2, nullptr, wtM1, bbuf, wr, wc, lane);
    do_gemm<256,256,1,4>(sm, p, R1, R2, wtM1, R0, R3, p.mb1,   wtM2, bbuf, wr, wc, lane);
    do_gemm<256,256,2,0>(sm, p, R0, R3, wtM2, 0,  0,  nullptr, nullptr, bbuf, wr, wc, lane);
    __syncthreads();
    // segmented reduction over sorted src: one atomic per (segment, col)
    {
        const int* srcid = (const int*)(sm + SRC_S);
        int h = tid >> 8;          // 0/1: rows 0..31 / 32..63
        int c = tid & 255;
        int rend = h * 32 + 31;
        float acc = 0.f;
        for (int r = h * 32; r <= rend; r++) {
            acc += *(const float*)(sm + dump_addr(r, c));
            if (r == rend || srcid[r + 1] != srcid[r]) {
                unsafeAtomicAdd(&p.xa[(size_t)srcid[r] * ND + c], acc);
                acc = 0.f;
            }
        }
    }
}

// ---------------- normalize: x_out = xa / den ----------------
__global__ void k_norm(const float* xa, const float* den, float* xout) {
    int i = blockIdx.x * 256 + threadIdx.x;
    if (i >= N_NODES * ND) return;
    float d = den[i >> 8];
    xout[i] = (d > 0.f) ? xa[i] / d : 0.f;
}

extern "C" void kernel_launch(void* const* d_in, const int* in_sizes, int n_in,
                              void* d_out, int out_size, void* d_ws, size_t ws_size,
                              hipStream_t stream) {
    const float* na  = (const float*)d_in[0];
    const float* ea  = (const float*)d_in[1];
    const int*   ei  = (const int*)d_in[2];
    const float* mw0 = (const float*)d_in[3];
    const float* mb0 = (const float*)d_in[4];
    const float* mw1 = (const float*)d_in[5];
    const float* mb1 = (const float*)d_in[6];
    const float* mw2 = (const float*)d_in[7];
    const float* mb2 = (const float*)d_in[8];
    const float* ew0 = (const float*)d_in[9];
    const float* eb0 = (const float*)d_in[10];
    const float* ew1 = (const float*)d_in[11];
    const float* eb1 = (const float*)d_in[12];
    const float* ew2 = (const float*)d_in[13];
    const float* eb2 = (const float*)d_in[14];
    const float* aw  = (const float*)d_in[15];
    const float* ab  = (const float*)d_in[16];
    float* out = (float*)d_out;
    char*  wsb = (char*)d_ws;

    float* xout = out;
    float* eout = out + (size_t)N_NODES * ND;

    float* xa  = (float*)(wsb + B_XA);
    float* den = (float*)(wsb + B_DEN);
    int*   cnt = (int*)(wsb + B_CNT);
    int*   row = (int*)(wsb + B_ROW);
    int*   cur = (int*)(wsb + B_CUR);
    int*   eidcsr = (int*)(wsb + B_EID);

    k_init<<<512, 256, 0, stream>>>(xa, den, cnt, cur);
    k_deg<<<1250, 256, 0, stream>>>(ei, cnt);
    k_scan<<<1, 256, 0, stream>>>(cnt, row);
    k_fill<<<1250, 256, 0, stream>>>(ei, row, cur, eidcsr);
    k_wconv<<<256, 256, 0, stream>>>(mw0, mw1, mw2, ew0, ew1, ew2, wsb + B_WT);
    k_nodepre<<<dim3(313, 4), 256, 0, stream>>>(na, mw0, ew0, aw, mb0, eb0, ab, wsb);

    DP p{ea, ei, eidcsr,
         (const unsigned short*)(wsb + B_AM), (const unsigned short*)(wsb + B_BM),
         (const unsigned short*)(wsb + B_AE), (const unsigned short*)(wsb + B_BE),
         (const float*)(wsb + B_P1), (const float*)(wsb + B_P2), aw,
         mb1, mb2, eb1, eb2, (const char*)(wsb + B_WT), xa, den, eout};
    hipFuncSetAttribute((const void*)k_main, hipFuncAttributeMaxDynamicSharedMemorySize, LDS_TOT);
    k_main<<<E_EDGES / BM, 512, LDS_TOT, stream>>>(p);
    k_norm<<<10000, 256, 0, stream>>>(xa, den, xout);
}